// Round 8
// baseline (326.743 us; speedup 1.0000x reference)
//
#include <hip/hip_runtime.h>
#include <math.h>

#define HID 128
typedef unsigned int uint;
typedef __attribute__((ext_vector_type(8))) __bf16 bf16x8;
typedef __attribute__((ext_vector_type(4))) float f32x4;
typedef __attribute__((ext_vector_type(2))) float f32x2;

// ---------------- bf16 helpers (RNE) ----------------

__device__ __forceinline__ uint pack_bf2(float x, float y) {
    union { float f; uint u; } a, b;
    a.f = x; b.f = y;
    uint lo = (a.u + 0x7fffu + ((a.u >> 16) & 1u)) >> 16;
    uint hi = (b.u + 0x7fffu + ((b.u >> 16) & 1u)) & 0xffff0000u;
    return lo | hi;
}

__device__ __forceinline__ unsigned short bf16r(float x) {
    union { float f; uint u; } a; a.f = x;
    return (unsigned short)((a.u + 0x7fffu + ((a.u >> 16) & 1u)) >> 16);
}

__device__ __forceinline__ f32x2 bf2f(uint v) {
    union { uint u[2]; f32x2 f; } r;
    r.u[0] = v << 16;
    r.u[1] = v & 0xffff0000u;
    return r.f;
}

__device__ __forceinline__ f32x2 mk2(float s) { f32x2 r; r.x = s; r.y = s; return r; }
__device__ __forceinline__ f32x2 max2z(f32x2 a) {
    f32x2 r; r.x = fmaxf(a.x, 0.f); r.y = fmaxf(a.y, 0.f); return r;
}
__device__ __forceinline__ f32x2 shfl_xor2(f32x2 v, int m) {
    f32x2 r; r.x = __shfl_xor(v.x, m, 64); r.y = __shfl_xor(v.y, m, 64); return r;
}

// ---------------- setup kernels ----------------

// zero cnt + zero zbias + composite weights:
//   Wc = W2 @ [Wm1_top | Wm1_mid]  (128 x 256), bf16 MFMA frag order
//   brow = b2 @ [Wm1_top | Wm1_mid] + [bm1 | 0]  (256)
__global__ void zero_prep(int* __restrict__ cnt, int N,
                          const float* __restrict__ W2, const float* __restrict__ Wm1,
                          const float* __restrict__ b2, const float* __restrict__ bm1,
                          uint* __restrict__ fWc, float* __restrict__ brow,
                          float* __restrict__ zbias) {
    int stride = gridDim.x * blockDim.x;
    int t0 = blockIdx.x * blockDim.x + threadIdx.x;
    for (int i = t0; i < N; i += stride) cnt[i] = 0;
    if (t0 < 128) zbias[t0] = 0.f;
    for (int i = t0; i < 16384; i += stride) {      // 16 ct * 4 kk * 64 lanes * 4 pairs
        int p = i & 3, lane = (i >> 2) & 63, kk = (i >> 8) & 3, ct = i >> 10;
        int k = kk * 32 + (lane >> 4) * 8 + p * 2;
        int n2 = ct * 16 + (lane & 15);
        const float* wmc = (n2 < 128) ? (Wm1 + n2) : (Wm1 + 128 * HID + (n2 - 128));
        const float* w2r0 = W2 + (size_t)k * HID;
        const float* w2r1 = w2r0 + HID;
        float d0 = 0.f, d1 = 0.f;
        for (int j = 0; j < HID; ++j) {
            float wm = wmc[(size_t)j * HID];
            d0 += w2r0[j] * wm;
            d1 += w2r1[j] * wm;
        }
        fWc[i] = pack_bf2(d0, d1);
    }
    for (int i = t0; i < 256; i += stride) {
        const float* wmc = (i < 128) ? (Wm1 + i) : (Wm1 + 128 * HID + (i - 128));
        float d = 0.f;
        for (int j = 0; j < HID; ++j) d += b2[j] * wmc[(size_t)j * HID];
        brow[i] = d + ((i < 128) ? bm1[i] : 0.f);
    }
}

__global__ void hist_kernel(const int* __restrict__ dst, int* __restrict__ cnt, int E) {
    int e = blockIdx.x * blockDim.x + threadIdx.x;
    if (e < E) atomicAdd(&cnt[dst[e]], 1);
}

__global__ void scan1(const int* __restrict__ cnt, int* __restrict__ excl,
                      int* __restrict__ bsum, int N) {
    __shared__ int sh[256];
    int tid = threadIdx.x;
    int gid = blockIdx.x * 256 + tid;
    int v = (gid < N) ? cnt[gid] : 0;
    sh[tid] = v;
    __syncthreads();
    for (int o = 1; o < 256; o <<= 1) {
        int t = (tid >= o) ? sh[tid - o] : 0;
        __syncthreads();
        sh[tid] += t;
        __syncthreads();
    }
    if (gid < N) excl[gid] = sh[tid] - v;
    if (tid == 255) bsum[blockIdx.x] = sh[255];
}

// every block redundantly scans bsum in LDS, finalizes rowptr/cursor/dis,
// and writes xps[n] = dis[n] * x[n] (padded to 8 floats)
__global__ void scan3x(const int* __restrict__ cnt, int* __restrict__ rowptr,
                       const int* __restrict__ bsum, int* __restrict__ cursor,
                       float* __restrict__ dis, const float* __restrict__ x,
                       float* __restrict__ xps, int N, int E, int NB) {
    __shared__ int sh[256];
    __shared__ int ex[256];
    int tid = threadIdx.x;
    int v = (tid < NB) ? bsum[tid] : 0;
    sh[tid] = v;
    __syncthreads();
    for (int o = 1; o < 256; o <<= 1) {
        int t = (tid >= o) ? sh[tid - o] : 0;
        __syncthreads();
        sh[tid] += t;
        __syncthreads();
    }
    ex[tid] = sh[tid] - v;
    __syncthreads();
    int gid = blockIdx.x * 256 + tid;
    if (gid < N) {
        int r = rowptr[gid] + ex[blockIdx.x];
        rowptr[gid] = r;
        cursor[gid] = r;
        float dn = rsqrtf((float)cnt[gid] + 1.0f);   // deg incl. self-loop
        dis[gid] = dn;
        const float* xr = x + (size_t)gid * 5;
        float* xo = xps + (size_t)gid * 8;
        *(float4*)xo = make_float4(dn * xr[0], dn * xr[1], dn * xr[2], dn * xr[3]);
        xo[4] = dn * xr[4];
    }
    if (gid == N) rowptr[N] = E;
}

// minimal scatter: csrc[pos] = src (4 B/edge scattered)
__global__ void scatter_kernel(const int* __restrict__ src, const int* __restrict__ dst,
                               int* __restrict__ cursor, int* __restrict__ csrc, int E) {
    int e = blockIdx.x * blockDim.x + threadIdx.x;
    if (e < E) {
        int pos = atomicAdd(&cursor[dst[e]], 1);
        csrc[pos] = src[e];
    }
}

// ---------------- feature kernels ----------------

// sx[n] = dis[n] * ( sum_{in(n)} xps[s] + xps[n] )   (5 dims, fp32, dis pre-folded)
__global__ void aggx_kernel(const float* __restrict__ xps, const int* __restrict__ csrc,
                            const int* __restrict__ rowptr, const float* __restrict__ dis,
                            float* __restrict__ sx, int N) {
    int n = blockIdx.x * blockDim.x + threadIdx.x;
    if (n >= N) return;
    int beg = rowptr[n], end = rowptr[n + 1];
    float a0 = 0.f, a1 = 0.f, a2 = 0.f, a3 = 0.f, a4 = 0.f;
    for (int i = beg; i < end; ++i) {
        int s = csrc[i];
        float4 v = *(const float4*)(xps + (size_t)s * 8);
        float v4 = xps[(size_t)s * 8 + 4];
        a0 += v.x; a1 += v.y; a2 += v.z; a3 += v.w; a4 += v4;
    }
    float4 v = *(const float4*)(xps + (size_t)n * 8);
    float v4 = xps[(size_t)n * 8 + 4];
    a0 += v.x; a1 += v.y; a2 += v.z; a3 += v.w; a4 += v4;
    float dn = dis[n];
    float* o = sx + (size_t)n * 8;
    *(float4*)o = make_float4(dn * a0, dn * a1, dn * a2, dn * a3);
    o[4] = dn * a4;
}

// hs1 = dis * relu(sx @ W1 + b1), bf16-packed
__global__ void hs1_kernel(const float* __restrict__ sx, const float* __restrict__ W1,
                           const float* __restrict__ b1, const float* __restrict__ dis,
                           uint* __restrict__ hs1, int N) {
    int idx = blockIdx.x * blockDim.x + threadIdx.x;
    if (idx >= N * 64) return;
    int n = idx >> 6, p = idx & 63;
    int j = p * 2;
    const float* sr = sx + (size_t)n * 8;
    float a0 = b1[j], a1 = b1[j + 1];
    #pragma unroll
    for (int k = 0; k < 5; ++k) {
        float s = sr[k];
        a0 += s * W1[k * HID + j];
        a1 += s * W1[k * HID + j + 1];
    }
    float dn = dis[n];
    a0 = fmaxf(a0, 0.f) * dn;
    a1 = fmaxf(a1, 0.f) * dn;
    hs1[idx] = pack_bf2(a0, a1);
}

// ---------------- hot kernels ----------------

// 128-dim aggregation: out[n] = bias + dis[n]*( sum_{in(n)} v[s] + v[n] ), bf16 out.
// wave per node; 16-lane group per edge; 4-deep => 16 edges in flight per wave.
__global__ void aggregate_kernel(const uint4* __restrict__ xws, const int* __restrict__ csrc,
                                 const int* __restrict__ rowptr, const float* __restrict__ dis,
                                 const float* __restrict__ bias, uint4* __restrict__ out,
                                 int N, int do_relu) {
    int wave = threadIdx.x >> 6;
    int lane = threadIdx.x & 63;
    int n = blockIdx.x * (blockDim.x >> 6) + wave;
    if (n >= N) return;
    int gl = lane & 15, grp = lane >> 4;
    int beg = rowptr[n], end = rowptr[n + 1];

    f32x2 acc[4];
    #pragma unroll
    for (int p = 0; p < 4; ++p) acc[p] = mk2(0.f);

    for (int base = beg + grp; base < end; base += 16) {
        int i1 = base + 4, i2 = base + 8, i3 = base + 12;
        int s0 = csrc[base];
        int s1 = csrc[(i1 < end) ? i1 : beg];
        int s2 = csrc[(i2 < end) ? i2 : beg];
        int s3 = csrc[(i3 < end) ? i3 : beg];
        uint4 v0 = xws[(size_t)s0 * 16 + gl];
        uint4 v1 = xws[(size_t)s1 * 16 + gl];
        uint4 v2 = xws[(size_t)s2 * 16 + gl];
        uint4 v3 = xws[(size_t)s3 * 16 + gl];
        f32x2 w1 = mk2((i1 < end) ? 1.f : 0.f);
        f32x2 w2 = mk2((i2 < end) ? 1.f : 0.f);
        f32x2 w3 = mk2((i3 < end) ? 1.f : 0.f);
        acc[0] += bf2f(v0.x);  acc[1] += bf2f(v0.y);
        acc[2] += bf2f(v0.z);  acc[3] += bf2f(v0.w);
        acc[0] += bf2f(v1.x) * w1;  acc[1] += bf2f(v1.y) * w1;
        acc[2] += bf2f(v1.z) * w1;  acc[3] += bf2f(v1.w) * w1;
        acc[0] += bf2f(v2.x) * w2;  acc[1] += bf2f(v2.y) * w2;
        acc[2] += bf2f(v2.z) * w2;  acc[3] += bf2f(v2.w) * w2;
        acc[0] += bf2f(v3.x) * w3;  acc[1] += bf2f(v3.y) * w3;
        acc[2] += bf2f(v3.z) * w3;  acc[3] += bf2f(v3.w) * w3;
    }
    #pragma unroll
    for (int p = 0; p < 4; ++p) {
        acc[p] += shfl_xor2(acc[p], 16);
        acc[p] += shfl_xor2(acc[p], 32);
    }

    if (grp == 0) {
        uint4 sv = xws[(size_t)n * 16 + gl];
        f32x2 dn = mk2(dis[n]);
        const float* bp = bias + gl * 8;
        f32x2 o[4];
        o[0] = (acc[0] + bf2f(sv.x)) * dn + *(const f32x2*)(bp);
        o[1] = (acc[1] + bf2f(sv.y)) * dn + *(const f32x2*)(bp + 2);
        o[2] = (acc[2] + bf2f(sv.z)) * dn + *(const f32x2*)(bp + 4);
        o[3] = (acc[3] + bf2f(sv.w)) * dn + *(const f32x2*)(bp + 6);
        if (do_relu) {
            #pragma unroll
            for (int p = 0; p < 4; ++p) o[p] = max2z(o[p]);
        }
        uint4 pk;
        pk.x = pack_bf2(o[0].x, o[0].y);
        pk.y = pack_bf2(o[1].x, o[1].y);
        pk.z = pack_bf2(o[2].x, o[2].y);
        pk.w = pack_bf2(o[3].x, o[3].y);
        out[(size_t)n * 16 + gl] = pk;
    }
}

// MFMA GEMM: out[N][CT*16] (bf16) = A[N][128]_bf16 @ Bf (+bias for ct<bias_ct)
__launch_bounds__(256)
__global__ void mfma_gemm(const uint4* __restrict__ A, const uint4* __restrict__ Bf,
                          const float* __restrict__ bias, const float* __restrict__ rowscale,
                          unsigned short* __restrict__ out, int N, int CT, int bias_ct) {
    int wave = threadIdx.x >> 6, lane = threadIdx.x & 63;
    int rbase = (blockIdx.x * 4 + wave) * 16;
    if (rbase >= N) return;
    int quad = lane >> 4, gl = lane & 15;
    int r = rbase + gl;
    if (r >= N) r = N - 1;

    bf16x8 afr[4];
    #pragma unroll
    for (int kk = 0; kk < 4; ++kk)
        afr[kk] = *(const bf16x8*)&A[(size_t)r * 16 + kk * 4 + quad];

    float rs[4];
    #pragma unroll
    for (int reg = 0; reg < 4; ++reg) {
        int row = rbase + quad * 4 + reg;
        rs[reg] = (rowscale && row < N) ? rowscale[row] : 1.f;
    }

    int ncols = CT * 16;
    for (int c = 0; c < CT; ++c) {
        f32x4 acc = {0.f, 0.f, 0.f, 0.f};
        #pragma unroll
        for (int kk = 0; kk < 4; ++kk) {
            bf16x8 bfr = *(const bf16x8*)&Bf[(size_t)(c * 4 + kk) * 64 + lane];
            acc = __builtin_amdgcn_mfma_f32_16x16x32_bf16(afr[kk], bfr, acc, 0, 0, 0);
        }
        float bv = (c < bias_ct) ? bias[c * 16 + gl] : 0.f;
        #pragma unroll
        for (int reg = 0; reg < 4; ++reg) {
            int row = rbase + quad * 4 + reg;
            if (row < N)
                out[(size_t)row * ncols + c * 16 + gl] = bf16r((acc[reg] + bv) * rs[reg]);
        }
    }
}

// edge-parallel edge MLP in ORIGINAL eid order: sequential src/dst/ea reads,
// coalesced out writes; 16-lane group per edge, 2-deep (8 edges per wave/iter).
__launch_bounds__(256)
__global__ void edge_mlp_kernel(const uint4* __restrict__ HsHd, const float4* __restrict__ ea,
                                const int* __restrict__ src, const int* __restrict__ dst,
                                const float* __restrict__ Wb, const float* __restrict__ Wm2,
                                const float* __restrict__ bm2,
                                float* __restrict__ out, int E) {
    int lane = threadIdx.x & 63;
    int gl = lane & 15, grp = lane >> 4;

    f32x2 wb[4][4], w2[4];
    #pragma unroll
    for (int k = 0; k < 4; ++k) {
        const f32x2* wp = (const f32x2*)(Wb + k * HID + gl * 8);
        #pragma unroll
        for (int p = 0; p < 4; ++p) wb[k][p] = wp[p];
    }
    {
        const f32x2* wp = (const f32x2*)(Wm2 + gl * 8);
        #pragma unroll
        for (int p = 0; p < 4; ++p) w2[p] = wp[p];
    }
    float b2v = bm2[0];

    int gwave = (blockIdx.x * blockDim.x + threadIdx.x) >> 6;
    int nw = (gridDim.x * blockDim.x) >> 6;
    for (int base = gwave * 8; base < E; base += nw * 8) {
        int i0 = base + grp;
        int i1 = i0 + 4;
        int j0 = (i0 < E) ? i0 : (E - 1);
        int j1 = (i1 < E) ? i1 : (E - 1);
        int s0i = src[j0], d0i = dst[j0];
        int s1i = src[j1], d1i = dst[j1];
        uint4 hv0 = HsHd[(size_t)s0i * 32 + gl];
        uint4 dv0 = HsHd[(size_t)d0i * 32 + 16 + gl];
        uint4 hv1 = HsHd[(size_t)s1i * 32 + gl];
        uint4 dv1 = HsHd[(size_t)d1i * 32 + 16 + gl];
        float4 ea0 = ea[j0];
        float4 ea1 = ea[j1];

        uint hu0[4] = {hv0.x, hv0.y, hv0.z, hv0.w};
        uint du0[4] = {dv0.x, dv0.y, dv0.z, dv0.w};
        uint hu1[4] = {hv1.x, hv1.y, hv1.z, hv1.w};
        uint du1[4] = {dv1.x, dv1.y, dv1.z, dv1.w};

        f32x2 p20 = mk2(0.f), p21 = mk2(0.f);
        f32x2 a0 = mk2(ea0.x), b0 = mk2(ea0.y), c0 = mk2(ea0.z), d0 = mk2(ea0.w);
        f32x2 a1 = mk2(ea1.x), b1 = mk2(ea1.y), c1 = mk2(ea1.z), d1 = mk2(ea1.w);
        #pragma unroll
        for (int p = 0; p < 4; ++p) {
            f32x2 t0 = bf2f(hu0[p]) + bf2f(du0[p]);
            t0 += a0 * wb[0][p];
            t0 += b0 * wb[1][p];
            t0 += c0 * wb[2][p];
            t0 += d0 * wb[3][p];
            t0 = max2z(t0);
            p20 += t0 * w2[p];
            f32x2 t1 = bf2f(hu1[p]) + bf2f(du1[p]);
            t1 += a1 * wb[0][p];
            t1 += b1 * wb[1][p];
            t1 += c1 * wb[2][p];
            t1 += d1 * wb[3][p];
            t1 = max2z(t1);
            p21 += t1 * w2[p];
        }
        float p0 = p20.x + p20.y;
        float p1 = p21.x + p21.y;
        p0 += __shfl_xor(p0, 1, 64);   p1 += __shfl_xor(p1, 1, 64);
        p0 += __shfl_xor(p0, 2, 64);   p1 += __shfl_xor(p1, 2, 64);
        p0 += __shfl_xor(p0, 4, 64);   p1 += __shfl_xor(p1, 4, 64);
        p0 += __shfl_xor(p0, 8, 64);   p1 += __shfl_xor(p1, 8, 64);
        if (gl == 0 && i0 < E) out[j0] = 1.f / (1.f + expf(-(p0 + b2v)));
        if (gl == 0 && i1 < E) out[j1] = 1.f / (1.f + expf(-(p1 + b2v)));
    }
}

// ---------------- launch ----------------

extern "C" void kernel_launch(void* const* d_in, const int* in_sizes, int n_in,
                              void* d_out, int out_size, void* d_ws, size_t ws_size,
                              hipStream_t stream) {
    const float* x    = (const float*)d_in[0];
    const float* ea   = (const float*)d_in[1];
    const float* W1   = (const float*)d_in[2];
    const float* b1   = (const float*)d_in[3];
    const float* W2   = (const float*)d_in[4];
    const float* b2   = (const float*)d_in[5];
    const float* Wm1  = (const float*)d_in[6];
    const float* bm1  = (const float*)d_in[7];
    const float* Wm2  = (const float*)d_in[8];
    const float* bm2  = (const float*)d_in[9];
    const int*   ei   = (const int*)d_in[10];

    const int N = in_sizes[0] / 5;
    const int E = in_sizes[1] / 4;
    const int* src = ei;
    const int* dst = ei + E;
    float* out = (float*)d_out;

    char* ws = (char*)d_ws;
    size_t off = 0;
    auto alloc = [&](size_t bytes) -> void* {
        void* p = ws + off;
        off = (off + bytes + 255) & ~(size_t)255;
        return p;
    };
    int*    cnt    = (int*)alloc((size_t)N * 4);
    int*    rowptr = (int*)alloc((size_t)(N + 1) * 4);
    int*    cursor = (int*)alloc((size_t)N * 4);
    int*    bsum   = (int*)alloc(256 * 4);
    float*  dis    = (float*)alloc((size_t)N * 4);
    int*    csrc   = (int*)alloc((size_t)(E + 8) * 4);
    float*  xps    = (float*)alloc((size_t)N * 8 * 4);
    float*  sx     = (float*)alloc((size_t)N * 8 * 4);
    uint*   R      = (uint*)alloc((size_t)N * 128 * 4);  // hs1 [N][64] then HsHd [N][128]
    uint*   g      = (uint*)alloc((size_t)N * 64 * 4);   // S·h1, bf16
    uint*   fWc    = (uint*)alloc(16384 * 4);
    float*  brow   = (float*)alloc(256 * 4);
    float*  zbias  = (float*)alloc(128 * 4);
    (void)ws_size; (void)n_in; (void)out_size;

    uint* hs1  = R;   // [N][64] uint (bf16 x 128) = dis * relu(sx@W1 + b1)
    uint* HsHd = R;   // [N][128] uint (bf16 x 256), overwrites hs1 (dead by then)

    const int NB = (N + 255) / 256;
    const int EB = (E + 255) / 256;

    // setup
    zero_prep<<<NB, 256, 0, stream>>>(cnt, N, W2, Wm1, b2, bm1, fWc, brow, zbias);
    hist_kernel<<<EB, 256, 0, stream>>>(dst, cnt, E);
    scan1<<<NB, 256, 0, stream>>>(cnt, rowptr, bsum, N);
    scan3x<<<NB, 256, 0, stream>>>(cnt, rowptr, bsum, cursor, dis, x, xps, N, E, NB);
    scatter_kernel<<<EB, 256, 0, stream>>>(src, dst, cursor, csrc, E);

    // layer 1 via commuted aggregation: sx = S·x (5-dim), hs1 = dis*relu(sx@W1+b1)
    aggx_kernel<<<NB, 256, 0, stream>>>(xps, csrc, rowptr, dis, sx, N);
    hs1_kernel<<<(N * 64 + 255) / 256, 256, 0, stream>>>(sx, W1, b1, dis, hs1, N);

    // g = S·h1  (the single 128-dim aggregate)
    aggregate_kernel<<<(N + 3) / 4, 256, 0, stream>>>((const uint4*)hs1, csrc, rowptr, dis,
                                                      zbias, (uint4*)g, N, 0);

    // HsHd = g @ Wc + brow   (fused W2 and Wm1 head GEMMs)
    mfma_gemm<<<(N + 63) / 64, 256, 0, stream>>>((const uint4*)g, (const uint4*)fWc,
                                                 brow, nullptr,
                                                 (unsigned short*)HsHd, N, 16, 16);

    // per-edge MLP + sigmoid, original eid order (sequential ea/src/dst, coalesced out)
    edge_mlp_kernel<<<2048, 256, 0, stream>>>((const uint4*)HsHd, (const float4*)ea,
                                              src, dst, Wm1 + 256 * HID, Wm2, bm2, out, E);
}

// Round 9
// 284.873 us; speedup vs baseline: 1.1470x; 1.1470x over previous
//
#include <hip/hip_runtime.h>
#include <math.h>

#define HID 128
typedef unsigned int uint;
typedef __attribute__((ext_vector_type(8))) __bf16 bf16x8;
typedef __attribute__((ext_vector_type(4))) float f32x4;
typedef __attribute__((ext_vector_type(2))) float f32x2;

// ---------------- bf16 helpers (RNE) ----------------

__device__ __forceinline__ uint pack_bf2(float x, float y) {
    union { float f; uint u; } a, b;
    a.f = x; b.f = y;
    uint lo = (a.u + 0x7fffu + ((a.u >> 16) & 1u)) >> 16;
    uint hi = (b.u + 0x7fffu + ((b.u >> 16) & 1u)) & 0xffff0000u;
    return lo | hi;
}

__device__ __forceinline__ unsigned short bf16r(float x) {
    union { float f; uint u; } a; a.f = x;
    return (unsigned short)((a.u + 0x7fffu + ((a.u >> 16) & 1u)) >> 16);
}

__device__ __forceinline__ f32x2 bf2f(uint v) {
    union { uint u[2]; f32x2 f; } r;
    r.u[0] = v << 16;
    r.u[1] = v & 0xffff0000u;
    return r.f;
}

__device__ __forceinline__ f32x2 mk2(float s) { f32x2 r; r.x = s; r.y = s; return r; }
__device__ __forceinline__ f32x2 max2z(f32x2 a) {
    f32x2 r; r.x = fmaxf(a.x, 0.f); r.y = fmaxf(a.y, 0.f); return r;
}
__device__ __forceinline__ f32x2 shfl_xor2(f32x2 v, int m) {
    f32x2 r; r.x = __shfl_xor(v.x, m, 64); r.y = __shfl_xor(v.y, m, 64); return r;
}

// ---------------- setup kernels ----------------

// zero cnt + zero zbias + composite weights:
//   Wc = W2 @ [Wm1_top | Wm1_mid]  (128 x 256), bf16 MFMA frag order
//   brow = b2 @ [Wm1_top | Wm1_mid] + [bm1 | 0]  (256)
__global__ void zero_prep(int* __restrict__ cnt, int N,
                          const float* __restrict__ W2, const float* __restrict__ Wm1,
                          const float* __restrict__ b2, const float* __restrict__ bm1,
                          uint* __restrict__ fWc, float* __restrict__ brow,
                          float* __restrict__ zbias) {
    int stride = gridDim.x * blockDim.x;
    int t0 = blockIdx.x * blockDim.x + threadIdx.x;
    for (int i = t0; i < N; i += stride) cnt[i] = 0;
    if (t0 < 128) zbias[t0] = 0.f;
    for (int i = t0; i < 16384; i += stride) {      // 16 ct * 4 kk * 64 lanes * 4 pairs
        int p = i & 3, lane = (i >> 2) & 63, kk = (i >> 8) & 3, ct = i >> 10;
        int k = kk * 32 + (lane >> 4) * 8 + p * 2;
        int n2 = ct * 16 + (lane & 15);
        const float* wmc = (n2 < 128) ? (Wm1 + n2) : (Wm1 + 128 * HID + (n2 - 128));
        const float* w2r0 = W2 + (size_t)k * HID;
        const float* w2r1 = w2r0 + HID;
        float d0 = 0.f, d1 = 0.f;
        for (int j = 0; j < HID; ++j) {
            float wm = wmc[(size_t)j * HID];
            d0 += w2r0[j] * wm;
            d1 += w2r1[j] * wm;
        }
        fWc[i] = pack_bf2(d0, d1);
    }
    for (int i = t0; i < 256; i += stride) {
        const float* wmc = (i < 128) ? (Wm1 + i) : (Wm1 + 128 * HID + (i - 128));
        float d = 0.f;
        for (int j = 0; j < HID; ++j) d += b2[j] * wmc[(size_t)j * HID];
        brow[i] = d + ((i < 128) ? bm1[i] : 0.f);
    }
}

// histogram + within-bucket rank (atomic return value)
__global__ void hist_rank(const int* __restrict__ dst, int* __restrict__ cnt,
                          int* __restrict__ rank, int E) {
    int e = blockIdx.x * blockDim.x + threadIdx.x;
    if (e < E) rank[e] = atomicAdd(&cnt[dst[e]], 1);
}

__global__ void scan1(const int* __restrict__ cnt, int* __restrict__ excl,
                      int* __restrict__ bsum, int N) {
    __shared__ int sh[256];
    int tid = threadIdx.x;
    int gid = blockIdx.x * 256 + tid;
    int v = (gid < N) ? cnt[gid] : 0;
    sh[tid] = v;
    __syncthreads();
    for (int o = 1; o < 256; o <<= 1) {
        int t = (tid >= o) ? sh[tid - o] : 0;
        __syncthreads();
        sh[tid] += t;
        __syncthreads();
    }
    if (gid < N) excl[gid] = sh[tid] - v;
    if (tid == 255) bsum[blockIdx.x] = sh[255];
}

// every block redundantly scans bsum in LDS, finalizes rowptr/dis,
// and writes xps[n] = dis[n] * x[n] (padded to 8 floats)
__global__ void scan3x(const int* __restrict__ cnt, int* __restrict__ rowptr,
                       const int* __restrict__ bsum,
                       float* __restrict__ dis, const float* __restrict__ x,
                       float* __restrict__ xps, int N, int E, int NB) {
    __shared__ int sh[256];
    __shared__ int ex[256];
    int tid = threadIdx.x;
    int v = (tid < NB) ? bsum[tid] : 0;
    sh[tid] = v;
    __syncthreads();
    for (int o = 1; o < 256; o <<= 1) {
        int t = (tid >= o) ? sh[tid - o] : 0;
        __syncthreads();
        sh[tid] += t;
        __syncthreads();
    }
    ex[tid] = sh[tid] - v;
    __syncthreads();
    int gid = blockIdx.x * 256 + tid;
    if (gid < N) {
        rowptr[gid] = rowptr[gid] + ex[blockIdx.x];
        float dn = rsqrtf((float)cnt[gid] + 1.0f);   // deg incl. self-loop
        dis[gid] = dn;
        const float* xr = x + (size_t)gid * 5;
        float* xo = xps + (size_t)gid * 8;
        *(float4*)xo = make_float4(dn * xr[0], dn * xr[1], dn * xr[2], dn * xr[3]);
        xo[4] = dn * xr[4];
    }
    if (gid == N) rowptr[N] = E;
}

// atomic-free scatter: pos = rowptr[dst] + rank; csr2[pos] = (src|dst<<16, eid)
__global__ void scatter2(const int* __restrict__ src, const int* __restrict__ dst,
                         const int* __restrict__ rowptr, const int* __restrict__ rank,
                         uint2* __restrict__ csr2, int E) {
    int e = blockIdx.x * blockDim.x + threadIdx.x;
    if (e < E) {
        int d = dst[e];
        int pos = rowptr[d] + rank[e];
        csr2[pos] = make_uint2((uint)src[e] | ((uint)d << 16), (uint)e);
    }
}

// ---------------- feature kernels ----------------

// sx[n] = dis[n] * ( sum_{in(n)} xps[s] + xps[n] )   (5 dims, fp32, dis pre-folded)
__global__ void aggx_kernel(const float* __restrict__ xps, const uint2* __restrict__ csr2,
                            const int* __restrict__ rowptr, const float* __restrict__ dis,
                            float* __restrict__ sx, int N) {
    int n = blockIdx.x * blockDim.x + threadIdx.x;
    if (n >= N) return;
    int beg = rowptr[n], end = rowptr[n + 1];
    float a0 = 0.f, a1 = 0.f, a2 = 0.f, a3 = 0.f, a4 = 0.f;
    for (int i = beg; i < end; ++i) {
        int s = (int)(csr2[i].x & 0xffffu);
        float4 v = *(const float4*)(xps + (size_t)s * 8);
        float v4 = xps[(size_t)s * 8 + 4];
        a0 += v.x; a1 += v.y; a2 += v.z; a3 += v.w; a4 += v4;
    }
    float4 v = *(const float4*)(xps + (size_t)n * 8);
    float v4 = xps[(size_t)n * 8 + 4];
    a0 += v.x; a1 += v.y; a2 += v.z; a3 += v.w; a4 += v4;
    float dn = dis[n];
    float* o = sx + (size_t)n * 8;
    *(float4*)o = make_float4(dn * a0, dn * a1, dn * a2, dn * a3);
    o[4] = dn * a4;
}

// hs1 = dis * relu(sx @ W1 + b1), bf16-packed
__global__ void hs1_kernel(const float* __restrict__ sx, const float* __restrict__ W1,
                           const float* __restrict__ b1, const float* __restrict__ dis,
                           uint* __restrict__ hs1, int N) {
    int idx = blockIdx.x * blockDim.x + threadIdx.x;
    if (idx >= N * 64) return;
    int n = idx >> 6, p = idx & 63;
    int j = p * 2;
    const float* sr = sx + (size_t)n * 8;
    float a0 = b1[j], a1 = b1[j + 1];
    #pragma unroll
    for (int k = 0; k < 5; ++k) {
        float s = sr[k];
        a0 += s * W1[k * HID + j];
        a1 += s * W1[k * HID + j + 1];
    }
    float dn = dis[n];
    a0 = fmaxf(a0, 0.f) * dn;
    a1 = fmaxf(a1, 0.f) * dn;
    hs1[idx] = pack_bf2(a0, a1);
}

// ---------------- hot kernels ----------------

// 128-dim aggregation: out[n] = bias + dis[n]*( sum_{in(n)} v[s] + v[n] ), bf16 out.
// wave per node; 16-lane group per edge; 4-deep => 16 edges in flight per wave.
__global__ void aggregate_kernel(const uint4* __restrict__ xws, const uint2* __restrict__ csr2,
                                 const int* __restrict__ rowptr, const float* __restrict__ dis,
                                 const float* __restrict__ bias, uint4* __restrict__ out,
                                 int N, int do_relu) {
    int wave = threadIdx.x >> 6;
    int lane = threadIdx.x & 63;
    int n = blockIdx.x * (blockDim.x >> 6) + wave;
    if (n >= N) return;
    int gl = lane & 15, grp = lane >> 4;
    int beg = rowptr[n], end = rowptr[n + 1];

    f32x2 acc[4];
    #pragma unroll
    for (int p = 0; p < 4; ++p) acc[p] = mk2(0.f);

    for (int base = beg + grp; base < end; base += 16) {
        int i1 = base + 4, i2 = base + 8, i3 = base + 12;
        int s0 = (int)(csr2[base].x & 0xffffu);
        int s1 = (int)(csr2[(i1 < end) ? i1 : beg].x & 0xffffu);
        int s2 = (int)(csr2[(i2 < end) ? i2 : beg].x & 0xffffu);
        int s3 = (int)(csr2[(i3 < end) ? i3 : beg].x & 0xffffu);
        uint4 v0 = xws[(size_t)s0 * 16 + gl];
        uint4 v1 = xws[(size_t)s1 * 16 + gl];
        uint4 v2 = xws[(size_t)s2 * 16 + gl];
        uint4 v3 = xws[(size_t)s3 * 16 + gl];
        f32x2 w1 = mk2((i1 < end) ? 1.f : 0.f);
        f32x2 w2 = mk2((i2 < end) ? 1.f : 0.f);
        f32x2 w3 = mk2((i3 < end) ? 1.f : 0.f);
        acc[0] += bf2f(v0.x);  acc[1] += bf2f(v0.y);
        acc[2] += bf2f(v0.z);  acc[3] += bf2f(v0.w);
        acc[0] += bf2f(v1.x) * w1;  acc[1] += bf2f(v1.y) * w1;
        acc[2] += bf2f(v1.z) * w1;  acc[3] += bf2f(v1.w) * w1;
        acc[0] += bf2f(v2.x) * w2;  acc[1] += bf2f(v2.y) * w2;
        acc[2] += bf2f(v2.z) * w2;  acc[3] += bf2f(v2.w) * w2;
        acc[0] += bf2f(v3.x) * w3;  acc[1] += bf2f(v3.y) * w3;
        acc[2] += bf2f(v3.z) * w3;  acc[3] += bf2f(v3.w) * w3;
    }
    #pragma unroll
    for (int p = 0; p < 4; ++p) {
        acc[p] += shfl_xor2(acc[p], 16);
        acc[p] += shfl_xor2(acc[p], 32);
    }

    if (grp == 0) {
        uint4 sv = xws[(size_t)n * 16 + gl];
        f32x2 dn = mk2(dis[n]);
        const float* bp = bias + gl * 8;
        f32x2 o[4];
        o[0] = (acc[0] + bf2f(sv.x)) * dn + *(const f32x2*)(bp);
        o[1] = (acc[1] + bf2f(sv.y)) * dn + *(const f32x2*)(bp + 2);
        o[2] = (acc[2] + bf2f(sv.z)) * dn + *(const f32x2*)(bp + 4);
        o[3] = (acc[3] + bf2f(sv.w)) * dn + *(const f32x2*)(bp + 6);
        if (do_relu) {
            #pragma unroll
            for (int p = 0; p < 4; ++p) o[p] = max2z(o[p]);
        }
        uint4 pk;
        pk.x = pack_bf2(o[0].x, o[0].y);
        pk.y = pack_bf2(o[1].x, o[1].y);
        pk.z = pack_bf2(o[2].x, o[2].y);
        pk.w = pack_bf2(o[3].x, o[3].y);
        out[(size_t)n * 16 + gl] = pk;
    }
}

// MFMA GEMM: out[N][CT*16] (bf16) = A[N][128]_bf16 @ Bf (+bias for ct<bias_ct)
__launch_bounds__(256)
__global__ void mfma_gemm(const uint4* __restrict__ A, const uint4* __restrict__ Bf,
                          const float* __restrict__ bias, const float* __restrict__ rowscale,
                          unsigned short* __restrict__ out, int N, int CT, int bias_ct) {
    int wave = threadIdx.x >> 6, lane = threadIdx.x & 63;
    int rbase = (blockIdx.x * 4 + wave) * 16;
    if (rbase >= N) return;
    int quad = lane >> 4, gl = lane & 15;
    int r = rbase + gl;
    if (r >= N) r = N - 1;

    bf16x8 afr[4];
    #pragma unroll
    for (int kk = 0; kk < 4; ++kk)
        afr[kk] = *(const bf16x8*)&A[(size_t)r * 16 + kk * 4 + quad];

    float rs[4];
    #pragma unroll
    for (int reg = 0; reg < 4; ++reg) {
        int row = rbase + quad * 4 + reg;
        rs[reg] = (rowscale && row < N) ? rowscale[row] : 1.f;
    }

    int ncols = CT * 16;
    for (int c = 0; c < CT; ++c) {
        f32x4 acc = {0.f, 0.f, 0.f, 0.f};
        #pragma unroll
        for (int kk = 0; kk < 4; ++kk) {
            bf16x8 bfr = *(const bf16x8*)&Bf[(size_t)(c * 4 + kk) * 64 + lane];
            acc = __builtin_amdgcn_mfma_f32_16x16x32_bf16(afr[kk], bfr, acc, 0, 0, 0);
        }
        float bv = (c < bias_ct) ? bias[c * 16 + gl] : 0.f;
        #pragma unroll
        for (int reg = 0; reg < 4; ++reg) {
            int row = rbase + quad * 4 + reg;
            if (row < N)
                out[(size_t)row * ncols + c * 16 + gl] = bf16r((acc[reg] + bv) * rs[reg]);
        }
    }
}

// edge-parallel edge MLP over dst-sorted csr2 (sequential 8 B entries);
// Hd[dst] dst-run L2-local; ea gathered by eid; out scattered 4 B.
__launch_bounds__(256)
__global__ void edge_mlp_kernel(const uint4* __restrict__ HsHd, const float4* __restrict__ ea,
                                const uint2* __restrict__ csr2,
                                const float* __restrict__ Wb, const float* __restrict__ Wm2,
                                const float* __restrict__ bm2,
                                float* __restrict__ out, int E) {
    int lane = threadIdx.x & 63;
    int gl = lane & 15, grp = lane >> 4;

    f32x2 wb[4][4], w2[4];
    #pragma unroll
    for (int k = 0; k < 4; ++k) {
        const f32x2* wp = (const f32x2*)(Wb + k * HID + gl * 8);
        #pragma unroll
        for (int p = 0; p < 4; ++p) wb[k][p] = wp[p];
    }
    {
        const f32x2* wp = (const f32x2*)(Wm2 + gl * 8);
        #pragma unroll
        for (int p = 0; p < 4; ++p) w2[p] = wp[p];
    }
    float b2v = bm2[0];

    int gwave = (blockIdx.x * blockDim.x + threadIdx.x) >> 6;
    int nw = (gridDim.x * blockDim.x) >> 6;
    for (int base = gwave * 8; base < E; base += nw * 8) {
        int i0 = base + grp;
        int i1 = i0 + 4;
        int j0 = (i0 < E) ? i0 : (E - 1);
        int j1 = (i1 < E) ? i1 : (E - 1);
        uint2 ce0 = csr2[j0];
        uint2 ce1 = csr2[j1];
        int s0i = (int)(ce0.x & 0xffffu), d0i = (int)(ce0.x >> 16);
        int s1i = (int)(ce1.x & 0xffffu), d1i = (int)(ce1.x >> 16);
        uint4 hv0 = HsHd[(size_t)s0i * 32 + gl];
        uint4 dv0 = HsHd[(size_t)d0i * 32 + 16 + gl];
        uint4 hv1 = HsHd[(size_t)s1i * 32 + gl];
        uint4 dv1 = HsHd[(size_t)d1i * 32 + 16 + gl];
        float4 ea0 = ea[ce0.y];
        float4 ea1 = ea[ce1.y];

        uint hu0[4] = {hv0.x, hv0.y, hv0.z, hv0.w};
        uint du0[4] = {dv0.x, dv0.y, dv0.z, dv0.w};
        uint hu1[4] = {hv1.x, hv1.y, hv1.z, hv1.w};
        uint du1[4] = {dv1.x, dv1.y, dv1.z, dv1.w};

        f32x2 p20 = mk2(0.f), p21 = mk2(0.f);
        f32x2 a0 = mk2(ea0.x), b0 = mk2(ea0.y), c0 = mk2(ea0.z), d0 = mk2(ea0.w);
        f32x2 a1 = mk2(ea1.x), b1 = mk2(ea1.y), c1 = mk2(ea1.z), d1 = mk2(ea1.w);
        #pragma unroll
        for (int p = 0; p < 4; ++p) {
            f32x2 t0 = bf2f(hu0[p]) + bf2f(du0[p]);
            t0 += a0 * wb[0][p];
            t0 += b0 * wb[1][p];
            t0 += c0 * wb[2][p];
            t0 += d0 * wb[3][p];
            t0 = max2z(t0);
            p20 += t0 * w2[p];
            f32x2 t1 = bf2f(hu1[p]) + bf2f(du1[p]);
            t1 += a1 * wb[0][p];
            t1 += b1 * wb[1][p];
            t1 += c1 * wb[2][p];
            t1 += d1 * wb[3][p];
            t1 = max2z(t1);
            p21 += t1 * w2[p];
        }
        float p0 = p20.x + p20.y;
        float p1 = p21.x + p21.y;
        p0 += __shfl_xor(p0, 1, 64);   p1 += __shfl_xor(p1, 1, 64);
        p0 += __shfl_xor(p0, 2, 64);   p1 += __shfl_xor(p1, 2, 64);
        p0 += __shfl_xor(p0, 4, 64);   p1 += __shfl_xor(p1, 4, 64);
        p0 += __shfl_xor(p0, 8, 64);   p1 += __shfl_xor(p1, 8, 64);
        if (gl == 0 && i0 < E) out[ce0.y] = 1.f / (1.f + expf(-(p0 + b2v)));
        if (gl == 0 && i1 < E) out[ce1.y] = 1.f / (1.f + expf(-(p1 + b2v)));
    }
}

// ---------------- launch ----------------

extern "C" void kernel_launch(void* const* d_in, const int* in_sizes, int n_in,
                              void* d_out, int out_size, void* d_ws, size_t ws_size,
                              hipStream_t stream) {
    const float* x    = (const float*)d_in[0];
    const float* ea   = (const float*)d_in[1];
    const float* W1   = (const float*)d_in[2];
    const float* b1   = (const float*)d_in[3];
    const float* W2   = (const float*)d_in[4];
    const float* b2   = (const float*)d_in[5];
    const float* Wm1  = (const float*)d_in[6];
    const float* bm1  = (const float*)d_in[7];
    const float* Wm2  = (const float*)d_in[8];
    const float* bm2  = (const float*)d_in[9];
    const int*   ei   = (const int*)d_in[10];

    const int N = in_sizes[0] / 5;
    const int E = in_sizes[1] / 4;
    const int* src = ei;
    const int* dst = ei + E;
    float* out = (float*)d_out;

    char* ws = (char*)d_ws;
    size_t off = 0;
    auto alloc = [&](size_t bytes) -> void* {
        void* p = ws + off;
        off = (off + bytes + 255) & ~(size_t)255;
        return p;
    };
    int*    cnt    = (int*)alloc((size_t)N * 4);
    int*    rowptr = (int*)alloc((size_t)(N + 1) * 4);
    int*    bsum   = (int*)alloc(256 * 4);
    float*  dis    = (float*)alloc((size_t)N * 4);
    int*    rank   = (int*)alloc((size_t)(E + 8) * 4);
    uint2*  csr2   = (uint2*)alloc((size_t)(E + 8) * 8);
    float*  xps    = (float*)alloc((size_t)N * 8 * 4);
    float*  sx     = (float*)alloc((size_t)N * 8 * 4);
    uint*   R      = (uint*)alloc((size_t)N * 128 * 4);  // hs1 [N][64] then HsHd [N][128]
    uint*   g      = (uint*)alloc((size_t)N * 64 * 4);   // S·h1, bf16
    uint*   fWc    = (uint*)alloc(16384 * 4);
    float*  brow   = (float*)alloc(256 * 4);
    float*  zbias  = (float*)alloc(128 * 4);
    (void)ws_size; (void)n_in; (void)out_size;

    uint* hs1  = R;   // [N][64] uint (bf16 x 128) = dis * relu(sx@W1 + b1)
    uint* HsHd = R;   // [N][128] uint (bf16 x 256), overwrites hs1 (dead by then)

    const int NB = (N + 255) / 256;
    const int EB = (E + 255) / 256;

    // setup
    zero_prep<<<NB, 256, 0, stream>>>(cnt, N, W2, Wm1, b2, bm1, fWc, brow, zbias);
    hist_rank<<<EB, 256, 0, stream>>>(dst, cnt, rank, E);
    scan1<<<NB, 256, 0, stream>>>(cnt, rowptr, bsum, N);
    scan3x<<<NB, 256, 0, stream>>>(cnt, rowptr, bsum, dis, x, xps, N, E, NB);
    scatter2<<<EB, 256, 0, stream>>>(src, dst, rowptr, rank, csr2, E);

    // layer 1 via commuted aggregation: sx = S·x (5-dim), hs1 = dis*relu(sx@W1+b1)
    aggx_kernel<<<NB, 256, 0, stream>>>(xps, csr2, rowptr, dis, sx, N);
    hs1_kernel<<<(N * 64 + 255) / 256, 256, 0, stream>>>(sx, W1, b1, dis, hs1, N);

    // g = S·h1  (the single 128-dim aggregate)
    aggregate_kernel<<<(N + 3) / 4, 256, 0, stream>>>((const uint4*)hs1, csr2, rowptr, dis,
                                                      zbias, (uint4*)g, N, 0);

    // HsHd = g @ Wc + brow   (fused W2 and Wm1 head GEMMs)
    mfma_gemm<<<(N + 63) / 64, 256, 0, stream>>>((const uint4*)g, (const uint4*)fWc,
                                                 brow, nullptr,
                                                 (unsigned short*)HsHd, N, 16, 16);

    // per-edge MLP + sigmoid, dst-sorted order
    edge_mlp_kernel<<<2048, 256, 0, stream>>>((const uint4*)HsHd, (const float4*)ea, csr2,
                                              Wm1 + 256 * HID, Wm2, bm2, out, E);
}

// Round 10
// 265.421 us; speedup vs baseline: 1.2310x; 1.0733x over previous
//
#include <hip/hip_runtime.h>
#include <math.h>

#define HID 128
typedef unsigned int uint;
typedef __attribute__((ext_vector_type(8))) __bf16 bf16x8;
typedef __attribute__((ext_vector_type(4))) float f32x4;
typedef __attribute__((ext_vector_type(2))) float f32x2;

// ---------------- bf16 helpers (RNE) ----------------

__device__ __forceinline__ uint pack_bf2(float x, float y) {
    union { float f; uint u; } a, b;
    a.f = x; b.f = y;
    uint lo = (a.u + 0x7fffu + ((a.u >> 16) & 1u)) >> 16;
    uint hi = (b.u + 0x7fffu + ((b.u >> 16) & 1u)) & 0xffff0000u;
    return lo | hi;
}

__device__ __forceinline__ unsigned short bf16r(float x) {
    union { float f; uint u; } a; a.f = x;
    return (unsigned short)((a.u + 0x7fffu + ((a.u >> 16) & 1u)) >> 16);
}

__device__ __forceinline__ f32x2 bf2f(uint v) {
    union { uint u[2]; f32x2 f; } r;
    r.u[0] = v << 16;
    r.u[1] = v & 0xffff0000u;
    return r.f;
}

__device__ __forceinline__ f32x2 mk2(float s) { f32x2 r; r.x = s; r.y = s; return r; }
__device__ __forceinline__ f32x2 max2z(f32x2 a) {
    f32x2 r; r.x = fmaxf(a.x, 0.f); r.y = fmaxf(a.y, 0.f); return r;
}
__device__ __forceinline__ f32x2 shfl_xor2(f32x2 v, int m) {
    f32x2 r; r.x = __shfl_xor(v.x, m, 64); r.y = __shfl_xor(v.y, m, 64); return r;
}

// ---------------- setup kernels ----------------

// zero cnt + composite weights:
//   Wc = W2 @ [Wm1_top | Wm1_mid]  (128 x 256), bf16 MFMA frag order
//   brow = b2 @ [Wm1_top | Wm1_mid] + [bm1 | 0]  (256)
__global__ void zero_prep(int* __restrict__ cnt, int N,
                          const float* __restrict__ W2, const float* __restrict__ Wm1,
                          const float* __restrict__ b2, const float* __restrict__ bm1,
                          uint* __restrict__ fWc, float* __restrict__ brow) {
    int stride = gridDim.x * blockDim.x;
    int t0 = blockIdx.x * blockDim.x + threadIdx.x;
    for (int i = t0; i < N; i += stride) cnt[i] = 0;
    for (int i = t0; i < 16384; i += stride) {      // 16 ct * 4 kk * 64 lanes * 4 pairs
        int p = i & 3, lane = (i >> 2) & 63, kk = (i >> 8) & 3, ct = i >> 10;
        int k = kk * 32 + (lane >> 4) * 8 + p * 2;
        int n2 = ct * 16 + (lane & 15);
        const float* wmc = (n2 < 128) ? (Wm1 + n2) : (Wm1 + 128 * HID + (n2 - 128));
        const float* w2r0 = W2 + (size_t)k * HID;
        const float* w2r1 = w2r0 + HID;
        float d0 = 0.f, d1 = 0.f;
        for (int j = 0; j < HID; ++j) {
            float wm = wmc[(size_t)j * HID];
            d0 += w2r0[j] * wm;
            d1 += w2r1[j] * wm;
        }
        fWc[i] = pack_bf2(d0, d1);
    }
    for (int i = t0; i < 256; i += stride) {
        const float* wmc = (i < 128) ? (Wm1 + i) : (Wm1 + 128 * HID + (i - 128));
        float d = 0.f;
        for (int j = 0; j < HID; ++j) d += b2[j] * wmc[(size_t)j * HID];
        brow[i] = d + ((i < 128) ? bm1[i] : 0.f);
    }
}

// histogram + within-bucket rank (atomic return value)
__global__ void hist_rank(const int* __restrict__ dst, int* __restrict__ cnt,
                          int* __restrict__ rank, int E) {
    int e = blockIdx.x * blockDim.x + threadIdx.x;
    if (e < E) rank[e] = atomicAdd(&cnt[dst[e]], 1);
}

__global__ void scan1(const int* __restrict__ cnt, int* __restrict__ excl,
                      int* __restrict__ bsum, int N) {
    __shared__ int sh[256];
    int tid = threadIdx.x;
    int gid = blockIdx.x * 256 + tid;
    int v = (gid < N) ? cnt[gid] : 0;
    sh[tid] = v;
    __syncthreads();
    for (int o = 1; o < 256; o <<= 1) {
        int t = (tid >= o) ? sh[tid - o] : 0;
        __syncthreads();
        sh[tid] += t;
        __syncthreads();
    }
    if (gid < N) excl[gid] = sh[tid] - v;
    if (tid == 255) bsum[blockIdx.x] = sh[255];
}

// every block redundantly scans bsum in LDS, finalizes rowptr/dis,
// and writes xps[n] = dis[n] * x[n] (padded to 8 floats)
__global__ void scan3x(const int* __restrict__ cnt, int* __restrict__ rowptr,
                       const int* __restrict__ bsum,
                       float* __restrict__ dis, const float* __restrict__ x,
                       float* __restrict__ xps, int N, int E, int NB) {
    __shared__ int sh[256];
    __shared__ int ex[256];
    int tid = threadIdx.x;
    int v = (tid < NB) ? bsum[tid] : 0;
    sh[tid] = v;
    __syncthreads();
    for (int o = 1; o < 256; o <<= 1) {
        int t = (tid >= o) ? sh[tid - o] : 0;
        __syncthreads();
        sh[tid] += t;
        __syncthreads();
    }
    ex[tid] = sh[tid] - v;
    __syncthreads();
    int gid = blockIdx.x * 256 + tid;
    if (gid < N) {
        rowptr[gid] = rowptr[gid] + ex[blockIdx.x];
        float dn = rsqrtf((float)cnt[gid] + 1.0f);   // deg incl. self-loop
        dis[gid] = dn;
        const float* xr = x + (size_t)gid * 5;
        float* xo = xps + (size_t)gid * 8;
        *(float4*)xo = make_float4(dn * xr[0], dn * xr[1], dn * xr[2], dn * xr[3]);
        xo[4] = dn * xr[4];
    }
    if (gid == N) rowptr[N] = E;
}

// atomic-free scatter: pos = rowptr[dst] + rank; csr2[pos] = (src|dst<<16, eid)
__global__ void scatter2(const int* __restrict__ src, const int* __restrict__ dst,
                         const int* __restrict__ rowptr, const int* __restrict__ rank,
                         uint2* __restrict__ csr2, int E) {
    int e = blockIdx.x * blockDim.x + threadIdx.x;
    if (e < E) {
        int d = dst[e];
        int pos = rowptr[d] + rank[e];
        csr2[pos] = make_uint2((uint)src[e] | ((uint)d << 16), (uint)e);
    }
}

// ---------------- fused layer-1: hs1 = dis * relu( (S·x) @ W1 + b1 ) ----------------
// one thread per node: 5-dim aggregate in registers, then 128-col expansion via LDS W1.
__launch_bounds__(256)
__global__ void layer1_kernel(const float* __restrict__ xps, const uint2* __restrict__ csr2,
                              const int* __restrict__ rowptr, const float* __restrict__ dis,
                              const float* __restrict__ W1, const float* __restrict__ b1,
                              uint* __restrict__ hs1, int N) {
    __shared__ float sW[5 * HID];
    __shared__ float sb[HID];
    int tid = threadIdx.x;
    for (int i = tid; i < 5 * HID; i += 256) sW[i] = W1[i];
    for (int i = tid; i < HID; i += 256) sb[i] = b1[i];
    __syncthreads();

    int n = blockIdx.x * 256 + tid;
    if (n >= N) return;
    int beg = rowptr[n], end = rowptr[n + 1];
    float a0 = 0.f, a1 = 0.f, a2 = 0.f, a3 = 0.f, a4 = 0.f;
    for (int i = beg; i < end; ++i) {
        int s = (int)(csr2[i].x & 0xffffu);
        float4 v = *(const float4*)(xps + (size_t)s * 8);
        float v4 = xps[(size_t)s * 8 + 4];
        a0 += v.x; a1 += v.y; a2 += v.z; a3 += v.w; a4 += v4;
    }
    {
        float4 v = *(const float4*)(xps + (size_t)n * 8);
        float v4 = xps[(size_t)n * 8 + 4];
        a0 += v.x; a1 += v.y; a2 += v.z; a3 += v.w; a4 += v4;
    }
    float dn = dis[n];
    a0 *= dn; a1 *= dn; a2 *= dn; a3 *= dn; a4 *= dn;   // sx row

    uint* op = hs1 + (size_t)n * 64;
    #pragma unroll 4
    for (int p = 0; p < 64; ++p) {
        int j = p * 2;
        float t0 = sb[j]     + a0 * sW[j]     + a1 * sW[HID + j]     + a2 * sW[2*HID + j]
                             + a3 * sW[3*HID + j] + a4 * sW[4*HID + j];
        float t1 = sb[j + 1] + a0 * sW[j + 1] + a1 * sW[HID + j + 1] + a2 * sW[2*HID + j + 1]
                             + a3 * sW[3*HID + j + 1] + a4 * sW[4*HID + j + 1];
        op[p] = pack_bf2(fmaxf(t0, 0.f) * dn, fmaxf(t1, 0.f) * dn);
    }
}

// ---------------- fused aggregate + GEMM ----------------
// block = 4 waves = 16 nodes.  Phase 1: each wave aggregates 4 nodes (16-lane group
// per edge, 4-deep) into LDS tile g[16][128] bf16.  Phase 2: each wave MFMAs the tile
// against 4 of 16 column-tiles of Wc, writes HsHd rows (+brow bias).
__launch_bounds__(256)
__global__ void agg_gemm(const uint4* __restrict__ hs1, const uint2* __restrict__ csr2,
                         const int* __restrict__ rowptr, const float* __restrict__ dis,
                         const uint4* __restrict__ Bf, const float* __restrict__ brow,
                         unsigned short* __restrict__ out, int N) {
    __shared__ uint gt[16][64];   // 16 nodes x 128 bf16 (packed)
    int wave = threadIdx.x >> 6, lane = threadIdx.x & 63;
    int gl = lane & 15, grp = lane >> 4;
    int nb = blockIdx.x * 16;

    // phase 1
    for (int q = 0; q < 4; ++q) {
        int r = wave * 4 + q;
        int n = nb + r;
        if (n < N) {
            int beg = rowptr[n], end = rowptr[n + 1];
            f32x2 acc[4];
            #pragma unroll
            for (int p = 0; p < 4; ++p) acc[p] = mk2(0.f);
            for (int base = beg + grp; base < end; base += 16) {
                int i1 = base + 4, i2 = base + 8, i3 = base + 12;
                int s0 = (int)(csr2[base].x & 0xffffu);
                int s1 = (int)(csr2[(i1 < end) ? i1 : beg].x & 0xffffu);
                int s2 = (int)(csr2[(i2 < end) ? i2 : beg].x & 0xffffu);
                int s3 = (int)(csr2[(i3 < end) ? i3 : beg].x & 0xffffu);
                uint4 v0 = hs1[(size_t)s0 * 16 + gl];
                uint4 v1 = hs1[(size_t)s1 * 16 + gl];
                uint4 v2 = hs1[(size_t)s2 * 16 + gl];
                uint4 v3 = hs1[(size_t)s3 * 16 + gl];
                f32x2 w1 = mk2((i1 < end) ? 1.f : 0.f);
                f32x2 w2 = mk2((i2 < end) ? 1.f : 0.f);
                f32x2 w3 = mk2((i3 < end) ? 1.f : 0.f);
                acc[0] += bf2f(v0.x);  acc[1] += bf2f(v0.y);
                acc[2] += bf2f(v0.z);  acc[3] += bf2f(v0.w);
                acc[0] += bf2f(v1.x) * w1;  acc[1] += bf2f(v1.y) * w1;
                acc[2] += bf2f(v1.z) * w1;  acc[3] += bf2f(v1.w) * w1;
                acc[0] += bf2f(v2.x) * w2;  acc[1] += bf2f(v2.y) * w2;
                acc[2] += bf2f(v2.z) * w2;  acc[3] += bf2f(v2.w) * w2;
                acc[0] += bf2f(v3.x) * w3;  acc[1] += bf2f(v3.y) * w3;
                acc[2] += bf2f(v3.z) * w3;  acc[3] += bf2f(v3.w) * w3;
            }
            #pragma unroll
            for (int p = 0; p < 4; ++p) {
                acc[p] += shfl_xor2(acc[p], 16);
                acc[p] += shfl_xor2(acc[p], 32);
            }
            if (grp == 0) {
                uint4 sv = hs1[(size_t)n * 16 + gl];
                f32x2 dn = mk2(dis[n]);
                f32x2 o0 = (acc[0] + bf2f(sv.x)) * dn;
                f32x2 o1 = (acc[1] + bf2f(sv.y)) * dn;
                f32x2 o2 = (acc[2] + bf2f(sv.z)) * dn;
                f32x2 o3 = (acc[3] + bf2f(sv.w)) * dn;
                gt[r][gl * 4]     = pack_bf2(o0.x, o0.y);
                gt[r][gl * 4 + 1] = pack_bf2(o1.x, o1.y);
                gt[r][gl * 4 + 2] = pack_bf2(o2.x, o2.y);
                gt[r][gl * 4 + 3] = pack_bf2(o3.x, o3.y);
            }
        } else if (grp == 0) {
            gt[r][gl * 4] = 0; gt[r][gl * 4 + 1] = 0;
            gt[r][gl * 4 + 2] = 0; gt[r][gl * 4 + 3] = 0;
        }
    }
    __syncthreads();

    // phase 2: wave handles ct = wave*4 .. wave*4+3
    int quad = lane >> 4;
    bf16x8 afr[4];
    #pragma unroll
    for (int kk = 0; kk < 4; ++kk)
        afr[kk] = *(const bf16x8*)&gt[gl][kk * 16 + quad * 4];

    for (int cc = 0; cc < 4; ++cc) {
        int c = wave * 4 + cc;
        f32x4 acc = {0.f, 0.f, 0.f, 0.f};
        #pragma unroll
        for (int kk = 0; kk < 4; ++kk) {
            bf16x8 bfr = *(const bf16x8*)&Bf[(size_t)(c * 4 + kk) * 64 + lane];
            acc = __builtin_amdgcn_mfma_f32_16x16x32_bf16(afr[kk], bfr, acc, 0, 0, 0);
        }
        float bv = brow[c * 16 + gl];
        #pragma unroll
        for (int reg = 0; reg < 4; ++reg) {
            int row = nb + quad * 4 + reg;
            if (row < N)
                out[(size_t)row * 256 + c * 16 + gl] = bf16r(acc[reg] + bv);
        }
    }
}

// edge-parallel edge MLP over dst-sorted csr2; 16-lane group takes 4 CONSECUTIVE
// edges (dst-run locality), 16 edges per wave per iteration.
__launch_bounds__(256)
__global__ void edge_mlp_kernel(const uint4* __restrict__ HsHd, const float4* __restrict__ ea,
                                const uint2* __restrict__ csr2,
                                const float* __restrict__ Wb, const float* __restrict__ Wm2,
                                const float* __restrict__ bm2,
                                float* __restrict__ out, int E) {
    int lane = threadIdx.x & 63;
    int gl = lane & 15, grp = lane >> 4;

    f32x2 wb[4][4], w2[4];
    #pragma unroll
    for (int k = 0; k < 4; ++k) {
        const f32x2* wp = (const f32x2*)(Wb + k * HID + gl * 8);
        #pragma unroll
        for (int p = 0; p < 4; ++p) wb[k][p] = wp[p];
    }
    {
        const f32x2* wp = (const f32x2*)(Wm2 + gl * 8);
        #pragma unroll
        for (int p = 0; p < 4; ++p) w2[p] = wp[p];
    }
    float b2v = bm2[0];

    int gwave = (blockIdx.x * blockDim.x + threadIdx.x) >> 6;
    int nw = (gridDim.x * blockDim.x) >> 6;
    for (int base = gwave * 16; base < E; base += nw * 16) {
        int i0 = base + grp * 4;
        uint2 ce[4];
        uint4 hv[4], dv[4];
        float4 eav[4];
        #pragma unroll
        for (int t = 0; t < 4; ++t) {
            int i = i0 + t;
            int j = (i < E) ? i : (E - 1);
            ce[t] = csr2[j];
            hv[t] = HsHd[(size_t)(ce[t].x & 0xffffu) * 32 + gl];
            dv[t] = HsHd[(size_t)(ce[t].x >> 16) * 32 + 16 + gl];
            eav[t] = ea[ce[t].y];
        }
        float pr[4];
        #pragma unroll
        for (int t = 0; t < 4; ++t) {
            uint hu[4] = {hv[t].x, hv[t].y, hv[t].z, hv[t].w};
            uint du[4] = {dv[t].x, dv[t].y, dv[t].z, dv[t].w};
            f32x2 e0 = mk2(eav[t].x), e1 = mk2(eav[t].y);
            f32x2 e2 = mk2(eav[t].z), e3 = mk2(eav[t].w);
            f32x2 p2 = mk2(0.f);
            #pragma unroll
            for (int p = 0; p < 4; ++p) {
                f32x2 tt = bf2f(hu[p]) + bf2f(du[p]);
                tt += e0 * wb[0][p];
                tt += e1 * wb[1][p];
                tt += e2 * wb[2][p];
                tt += e3 * wb[3][p];
                tt = max2z(tt);
                p2 += tt * w2[p];
            }
            pr[t] = p2.x + p2.y;
        }
        #pragma unroll
        for (int o = 1; o <= 8; o <<= 1) {
            #pragma unroll
            for (int t = 0; t < 4; ++t) pr[t] += __shfl_xor(pr[t], o, 64);
        }
        if (gl == 0) {
            #pragma unroll
            for (int t = 0; t < 4; ++t) {
                int i = i0 + t;
                if (i < E) out[ce[t].y] = 1.f / (1.f + expf(-(pr[t] + b2v)));
            }
        }
    }
}

// ---------------- launch ----------------

extern "C" void kernel_launch(void* const* d_in, const int* in_sizes, int n_in,
                              void* d_out, int out_size, void* d_ws, size_t ws_size,
                              hipStream_t stream) {
    const float* x    = (const float*)d_in[0];
    const float* ea   = (const float*)d_in[1];
    const float* W1   = (const float*)d_in[2];
    const float* b1   = (const float*)d_in[3];
    const float* W2   = (const float*)d_in[4];
    const float* b2   = (const float*)d_in[5];
    const float* Wm1  = (const float*)d_in[6];
    const float* bm1  = (const float*)d_in[7];
    const float* Wm2  = (const float*)d_in[8];
    const float* bm2  = (const float*)d_in[9];
    const int*   ei   = (const int*)d_in[10];

    const int N = in_sizes[0] / 5;
    const int E = in_sizes[1] / 4;
    const int* src = ei;
    const int* dst = ei + E;
    float* out = (float*)d_out;

    char* ws = (char*)d_ws;
    size_t off = 0;
    auto alloc = [&](size_t bytes) -> void* {
        void* p = ws + off;
        off = (off + bytes + 255) & ~(size_t)255;
        return p;
    };
    int*    cnt    = (int*)alloc((size_t)N * 4);
    int*    rowptr = (int*)alloc((size_t)(N + 1) * 4);
    int*    bsum   = (int*)alloc(256 * 4);
    float*  dis    = (float*)alloc((size_t)N * 4);
    int*    rank   = (int*)alloc((size_t)(E + 8) * 4);
    uint2*  csr2   = (uint2*)alloc((size_t)(E + 8) * 8);
    float*  xps    = (float*)alloc((size_t)N * 8 * 4);
    uint*   hs1    = (uint*)alloc((size_t)N * 64 * 4);   // bf16 layer-1 features
    uint*   HsHd   = (uint*)alloc((size_t)N * 128 * 4);  // bf16 [N][256]
    uint*   fWc    = (uint*)alloc(16384 * 4);
    float*  brow   = (float*)alloc(256 * 4);
    (void)ws_size; (void)n_in; (void)out_size;

    const int NB = (N + 255) / 256;
    const int EB = (E + 255) / 256;

    // setup
    zero_prep<<<NB, 256, 0, stream>>>(cnt, N, W2, Wm1, b2, bm1, fWc, brow);
    hist_rank<<<EB, 256, 0, stream>>>(dst, cnt, rank, E);
    scan1<<<NB, 256, 0, stream>>>(cnt, rowptr, bsum, N);
    scan3x<<<NB, 256, 0, stream>>>(cnt, rowptr, bsum, dis, x, xps, N, E, NB);
    scatter2<<<EB, 256, 0, stream>>>(src, dst, rowptr, rank, csr2, E);

    // layer 1 fused: hs1 = dis * relu((S·x)@W1 + b1)
    layer1_kernel<<<NB, 256, 0, stream>>>(xps, csr2, rowptr, dis, W1, b1, hs1, N);

    // fused: g = S·h1 (LDS tile) ; HsHd = g @ Wc + brow
    agg_gemm<<<(N + 15) / 16, 256, 0, stream>>>((const uint4*)hs1, csr2, rowptr, dis,
                                                (const uint4*)fWc, brow,
                                                (unsigned short*)HsHd, N);

    // per-edge MLP + sigmoid, dst-sorted order
    edge_mlp_kernel<<<2048, 256, 0, stream>>>((const uint4*)HsHd, (const float4*)ea, csr2,
                                              Wm1 + 256 * HID, Wm2, bm2, out, E);
}